// Round 9
// baseline (619.568 us; speedup 1.0000x reference)
//
#include <hip/hip_runtime.h>

#define HD 50
#define TT 512
#define BRR 16        // batch rows per block -> 256 blocks = 1/CU
#define TC 32         // x prefetch chunk (timesteps)
#define HS 72         // shorts per h row (144B stride; b128 A-reads bank-balanced)

using bf16x8 = __attribute__((ext_vector_type(8))) short;
using f32x4  = __attribute__((ext_vector_type(4))) float;

__device__ __forceinline__ unsigned short f2bf(float f) {   // RNE float->bf16
    unsigned int u = __float_as_uint(f);
    u += 0x7FFFu + ((u >> 16) & 1u);
    return (unsigned short)(u >> 16);
}
__device__ __forceinline__ float bf2f(unsigned short b) {
    return __uint_as_float(((unsigned int)b) << 16);
}
__device__ __forceinline__ float frcp(float x) { return __builtin_amdgcn_rcpf(x); }
__device__ __forceinline__ float sigf(float x) { return frcp(1.0f + __expf(-x)); }
__device__ __forceinline__ float tanhfast(float x) {
    return 1.0f - 2.0f * frcp(__expf(2.0f * x) + 1.0f);
}

// r8 structure (gate-major tiles, in-register EW, 1 barrier/tick) + L1 lag-2:
//   tick n: waves 0-3 = L0 step n; waves 4-7 = L1 step n-2.
// PathB's h0 operand (h0(n-2)) is final one tick early -> prefetched into
// registers during tick n-1 (latency fully hidden). h1 operand read at tick
// top, hidden under the 24 prefetched-h0 MFMAs. h0 triple-buffered (idx n%3),
// h1 double-buffered (idx (n-2)&1).
__global__ __launch_bounds__(512, 2) void lstm2_mfma6(
    const float* __restrict__ x,
    const float* __restrict__ Wih0, const float* __restrict__ Whh0,
    const float* __restrict__ bih0, const float* __restrict__ bhh0,
    const float* __restrict__ Wih1, const float* __restrict__ Whh1,
    const float* __restrict__ bih1, const float* __restrict__ bhh1,
    const float* __restrict__ Wfc, const float* __restrict__ bfc,
    float* __restrict__ out)
{
    __shared__ short s_h0hi[3][BRR][HS], s_h0lo[3][BRR][HS]; // k: 0-49 h0, 50-52 x, 53+ 0
    __shared__ short s_h1hi[2][BRR][HS], s_h1lo[2][BRR][HS]; // k: 0-49 h1, 50+ 0
    __shared__ float s_xs[2][BRR][TC*3];

    const int tid  = threadIdx.x;
    const int wid  = tid >> 6;
    const int lane = tid & 63;
    const int lr   = lane & 15;    // B/D column = unit slot
    const int lq   = lane >> 4;    // k-octet / D row-quad
    const int r0   = blockIdx.x * BRR;
    const bool pathA = (wid < 4);
    const int  wsub  = wid & 3;
    const int  u     = lr * 4 + wsub;      // this lane's hidden unit
    const bool valid = (u < HD);

    // ---- weight B-fragments (hi/lo), register-resident; tile tt = gate type ----
    bf16x8 bh[4][4], bl[4][4];
    float bvT[4];
    #pragma unroll
    for (int tt = 0; tt < 4; ++tt) {
        #pragma unroll
        for (int s = 0; s < 4; ++s) { bh[tt][s] = (bf16x8)0; bl[tt][s] = (bf16x8)0; }
        const int g = tt * HD + (valid ? u : 0);     // gate-row in [0,200)
        if (pathA) {
            bvT[tt] = valid ? bih0[g] + bhh0[g] : 0.f;
            #pragma unroll
            for (int s = 0; s < 2; ++s) {
                #pragma unroll
                for (int j = 0; j < 8; ++j) {
                    const int k = s*32 + lq*8 + j;
                    float wv = 0.f;
                    if (valid) {
                        if (k < HD) wv = Whh0[g*HD + k];
                        else if (k < HD+3) wv = Wih0[g*3 + (k-HD)];
                    }
                    const unsigned short hb = f2bf(wv);
                    bh[tt][s][j] = (short)hb;
                    bl[tt][s][j] = (short)f2bf(wv - bf2f(hb));
                }
            }
        } else {
            bvT[tt] = valid ? bih1[g] + bhh1[g] : 0.f;
            #pragma unroll
            for (int s = 0; s < 4; ++s) {
                #pragma unroll
                for (int j = 0; j < 8; ++j) {
                    const int k = s*32 + lq*8 + j;   // 0-63: Wih1 k-space, 64-127: Whh1
                    float wv = 0.f;
                    if (valid) {
                        if (k < HD) wv = Wih1[g*HD + k];
                        else if (k >= 64 && k < 64+HD) wv = Whh1[g*HD + (k-64)];
                    }
                    const unsigned short hb = f2bf(wv);
                    bh[tt][s][j] = (short)hb;
                    bl[tt][s][j] = (short)f2bf(wv - bf2f(hb));
                }
            }
        }
    }

    // ---- per-lane c-state: 4 batch rows (4*lq+j) of unit u ----
    float cst[4] = {0.f, 0.f, 0.f, 0.f};

    // ---- x duty: tids 0-47 (subset of wave 0, pathA) ----
    const bool xth = (tid < 48);
    const int  xr  = tid / 3, xd = tid % 3;

    // ---- init LDS ----
    for (int p = tid; p < 3*BRR*HS; p += 512) {
        ((short*)s_h0hi)[p] = 0; ((short*)s_h0lo)[p] = 0;
    }
    for (int p = tid; p < 2*BRR*HS; p += 512) {
        ((short*)s_h1hi)[p] = 0; ((short*)s_h1lo)[p] = 0;
    }
    for (int p = tid; p < BRR*TC*3; p += 512) {       // stage x chunk 0
        const int rr = p / (TC*3), q = p % (TC*3);
        s_xs[0][rr][q] = x[(size_t)(r0+rr)*(TT*3) + q];
    }
    __syncthreads();
    if (xth) {                                        // x(0) -> h0 buf 2 (ridx at n=0)
        const float xv = s_xs[0][xr][xd];
        const unsigned short xh = f2bf(xv);
        s_h0hi[2][xr][HD+xd] = (short)xh;
        s_h0lo[2][xr][HD+xd] = (short)f2bf(xv - bf2f(xh));
    }
    __syncthreads();

    // pathB prefetch registers (h0 fragment pair for next tick)
    bf16x8 pfh0 = (bf16x8)0, pfh1 = (bf16x8)0, pfl0 = (bf16x8)0, pfl1 = (bf16x8)0;

    // ================= main loop: TT+2 ticks, ONE barrier each =================
    for (int n = 0; n <= TT + 1; ++n) {
        const int ridx = (n + 2) % 3;                  // h0(n-1)
        const int widx = n % 3;                        // h0(n)
        if (pathA) {
            if (n < TT) {                              // pre0(n) = [h0(n-1)|x(n)] @ W0
                const char* hb0 = (const char*)&s_h0hi[ridx][0][0];
                const char* lb0 = (const char*)&s_h0lo[ridx][0][0];
                bf16x8 ah[2], al[2];
                #pragma unroll
                for (int s = 0; s < 2; ++s) {
                    const int off = lr*(2*HS) + s*64 + lq*16;
                    ah[s] = *(const bf16x8*)(hb0 + off);
                    al[s] = *(const bf16x8*)(lb0 + off);
                }
                f32x4 acc[4];
                #pragma unroll
                for (int tt = 0; tt < 4; ++tt) { const float b = bvT[tt]; acc[tt] = (f32x4){b,b,b,b}; }
                #pragma unroll
                for (int s = 0; s < 2; ++s) {
                    #pragma unroll
                    for (int tt = 0; tt < 4; ++tt)
                        acc[tt] = __builtin_amdgcn_mfma_f32_16x16x32_bf16(ah[s], bh[tt][s], acc[tt], 0,0,0);
                    #pragma unroll
                    for (int tt = 0; tt < 4; ++tt)
                        acc[tt] = __builtin_amdgcn_mfma_f32_16x16x32_bf16(al[s], bh[tt][s], acc[tt], 0,0,0);
                    #pragma unroll
                    for (int tt = 0; tt < 4; ++tt)
                        acc[tt] = __builtin_amdgcn_mfma_f32_16x16x32_bf16(ah[s], bl[tt][s], acc[tt], 0,0,0);
                }
                if (valid) {                           // EW0 in-register -> h0(n) in buf[widx]
                    #pragma unroll
                    for (int j = 0; j < 4; ++j) {
                        const float iv = sigf(acc[0][j]);
                        const float fv = sigf(acc[1][j]);
                        const float gv = tanhfast(acc[2][j]);
                        const float ov = sigf(acc[3][j]);
                        const float c  = fv*cst[j] + iv*gv;
                        cst[j] = c;
                        const float h  = ov*tanhfast(c);
                        const unsigned short hb2 = f2bf(h);
                        s_h0hi[widx][lq*4+j][u] = (short)hb2;
                        s_h0lo[widx][lq*4+j][u] = (short)f2bf(h - bf2f(hb2));
                    }
                }
            }
            if (xth && (n+1) < TT) {                   // x(n+1) -> h0 buf[widx] k-slots 50-52
                const int tn = n + 1;
                const float xv = s_xs[(tn/TC)&1][xr][(tn%TC)*3 + xd];
                const unsigned short xh = f2bf(xv);
                s_h0hi[widx][xr][HD+xd] = (short)xh;
                s_h0lo[widx][xr][HD+xd] = (short)f2bf(xv - bf2f(xh));
            }
        } else {
            // ---- h1(n-3) fragments (k-slots 2,3): issue reads at tick top ----
            const char* hb1 = (const char*)&s_h1hi[(n+1)&1][0][0];
            const char* lb1 = (const char*)&s_h1lo[(n+1)&1][0][0];
            bf16x8 a1h[2], a1l[2];
            #pragma unroll
            for (int ss = 0; ss < 2; ++ss) {
                const int off = lr*(2*HS) + ss*64 + lq*16;
                a1h[ss] = *(const bf16x8*)(hb1 + off);
                a1l[ss] = *(const bf16x8*)(lb1 + off);
            }
            f32x4 acc[4];
            if (n >= 2) {                              // pre1(n-2) = [h0(n-2)|h1(n-3)] @ W1
                #pragma unroll
                for (int tt = 0; tt < 4; ++tt) { const float b = bvT[tt]; acc[tt] = (f32x4){b,b,b,b}; }
                // s=0,1 on PREFETCHED h0(n-2) regs (no LDS wait)
                #pragma unroll
                for (int tt = 0; tt < 4; ++tt)
                    acc[tt] = __builtin_amdgcn_mfma_f32_16x16x32_bf16(pfh0, bh[tt][0], acc[tt], 0,0,0);
                #pragma unroll
                for (int tt = 0; tt < 4; ++tt)
                    acc[tt] = __builtin_amdgcn_mfma_f32_16x16x32_bf16(pfl0, bh[tt][0], acc[tt], 0,0,0);
                #pragma unroll
                for (int tt = 0; tt < 4; ++tt)
                    acc[tt] = __builtin_amdgcn_mfma_f32_16x16x32_bf16(pfh0, bl[tt][0], acc[tt], 0,0,0);
                #pragma unroll
                for (int tt = 0; tt < 4; ++tt)
                    acc[tt] = __builtin_amdgcn_mfma_f32_16x16x32_bf16(pfh1, bh[tt][1], acc[tt], 0,0,0);
                #pragma unroll
                for (int tt = 0; tt < 4; ++tt)
                    acc[tt] = __builtin_amdgcn_mfma_f32_16x16x32_bf16(pfl1, bh[tt][1], acc[tt], 0,0,0);
                #pragma unroll
                for (int tt = 0; tt < 4; ++tt)
                    acc[tt] = __builtin_amdgcn_mfma_f32_16x16x32_bf16(pfh1, bl[tt][1], acc[tt], 0,0,0);
            }
            // ---- prefetch h0(n-1) for NEXT tick (overwrites pf after last use) ----
            {
                const char* phb = (const char*)&s_h0hi[ridx][0][0];
                const char* plb = (const char*)&s_h0lo[ridx][0][0];
                const int off0 = lr*(2*HS) + lq*16;
                pfh0 = *(const bf16x8*)(phb + off0);
                pfh1 = *(const bf16x8*)(phb + off0 + 64);
                pfl0 = *(const bf16x8*)(plb + off0);
                pfl1 = *(const bf16x8*)(plb + off0 + 64);
            }
            if (n >= 2) {
                // s=2,3 on h1 regs (reads issued at tick top, hidden by s01 MFMAs)
                #pragma unroll
                for (int ss = 0; ss < 2; ++ss) {
                    #pragma unroll
                    for (int tt = 0; tt < 4; ++tt)
                        acc[tt] = __builtin_amdgcn_mfma_f32_16x16x32_bf16(a1h[ss], bh[tt][2+ss], acc[tt], 0,0,0);
                    #pragma unroll
                    for (int tt = 0; tt < 4; ++tt)
                        acc[tt] = __builtin_amdgcn_mfma_f32_16x16x32_bf16(a1l[ss], bh[tt][2+ss], acc[tt], 0,0,0);
                    #pragma unroll
                    for (int tt = 0; tt < 4; ++tt)
                        acc[tt] = __builtin_amdgcn_mfma_f32_16x16x32_bf16(a1h[ss], bl[tt][2+ss], acc[tt], 0,0,0);
                }
                if (valid) {                           // EW1 -> h1(n-2) in buf[n&1]
                    #pragma unroll
                    for (int j = 0; j < 4; ++j) {
                        const float iv = sigf(acc[0][j]);
                        const float fv = sigf(acc[1][j]);
                        const float gv = tanhfast(acc[2][j]);
                        const float ov = sigf(acc[3][j]);
                        const float c  = fv*cst[j] + iv*gv;
                        cst[j] = c;
                        const float h  = ov*tanhfast(c);
                        const unsigned short hb2 = f2bf(h);
                        s_h1hi[n&1][lq*4+j][u] = (short)hb2;
                        s_h1lo[n&1][lq*4+j][u] = (short)f2bf(h - bf2f(hb2));
                    }
                }
            }
        }
        {
            const int t2s = n + 2;                     // stage next x chunk 2 ticks ahead
            if (t2s < TT && (t2s % TC) == 0) {
                const int cb = (t2s / TC) & 1;
                for (int p = tid; p < BRR*TC*3; p += 512) {
                    const int rr = p / (TC*3), q = p % (TC*3);
                    s_xs[cb][rr][q] = x[(size_t)(r0+rr)*(TT*3) + (size_t)t2s*3 + q];
                }
            }
        }
        __syncthreads();
    }

    // ---- FC epilogue: out = h1(TT-1) @ Wfc^T + bfc  (h1(511) in buf[511&1]=1) ----
    if (tid < BRR*7) {
        const int r = tid / 7, o = tid % 7;
        float acc = bfc[o];
        #pragma unroll
        for (int uu = 0; uu < HD; ++uu)
            acc += (bf2f((unsigned short)s_h1hi[1][r][uu]) + bf2f((unsigned short)s_h1lo[1][r][uu])) * Wfc[o*HD + uu];
        out[(size_t)(r0+r)*7 + o] = acc;
    }
}

extern "C" void kernel_launch(void* const* d_in, const int* in_sizes, int n_in,
                              void* d_out, int out_size, void* d_ws, size_t ws_size,
                              hipStream_t stream) {
    const float* xp    = (const float*)d_in[0];
    const float* Wih0  = (const float*)d_in[1];
    const float* Whh0  = (const float*)d_in[2];
    const float* bih0  = (const float*)d_in[3];
    const float* bhh0  = (const float*)d_in[4];
    const float* Wih1  = (const float*)d_in[5];
    const float* Whh1  = (const float*)d_in[6];
    const float* bih1  = (const float*)d_in[7];
    const float* bhh1  = (const float*)d_in[8];
    const float* Wfc   = (const float*)d_in[9];
    const float* bfc   = (const float*)d_in[10];
    float* outp = (float*)d_out;

    const int B = in_sizes[0] / (TT * 3);   // 4096
    const int grid = B / BRR;               // 256 blocks, 1 per CU

    lstm2_mfma6<<<grid, 512, 0, stream>>>(
        xp, Wih0, Whh0, bih0, bhh0, Wih1, Whh1, bih1, bhh1, Wfc, bfc, outp);
}